// Round 5
// baseline (970.254 us; speedup 1.0000x reference)
//
#include <hip/hip_runtime.h>
#include <math.h>

// ---------------------------------------------------------------------------
// voting / segment-mean / argmax — R3 kernel + DUPLICATE phase-A launch probe
// shapes (fixed dataset): B=512, T=50, N=6400, L=10
// ws layout: part[NR][N] float, NR = HS*B (HS=2 t-halves)  (26 MB)
//
// MEASUREMENT ROUND (resubmit; R4 failed on container infra, not kernel):
// sumT_lin_k is launched TWICE (idempotent: const input, deterministic
// overwrite of part). dur_us minus R3's 852.2 µs = true cost of one
// sumT_lin dispatch, never visible in top-5 counter rows. Phase B and all
// math identical to R3 -> absmax unchanged.
// ---------------------------------------------------------------------------

#define L_FIXED 10

// Phase A: part[r][n] = sum over t-range of spikes[b,t,n], r = h*B + b.
// Block = one (b, h). 320 threads, each owns 5 float4 columns in registers.
__global__ void __launch_bounds__(320) sumT_lin_k(
    const float* __restrict__ spikes, float* __restrict__ part,
    int B, int T, int N, int HS) {
    const int r = blockIdx.x;        // row in [0, HS*B)
    const int h = r / B;
    const int b = r - h * B;
    const int t0 = (T * h) / HS;
    const int t1 = (T * (h + 1)) / HS;
    const int V = N >> 2;
    const int tid = threadIdx.x;
    const float4* p = (const float4*)(spikes + (size_t)b * T * N);
    float4* dst = (float4*)(part + (size_t)r * N);

    for (int v0 = 0; v0 < V; v0 += 1600) {            // one pass for N=6400
        float4 a0 = make_float4(0.f, 0.f, 0.f, 0.f);
        float4 a1 = a0, a2 = a0, a3 = a0, a4 = a0;
        const int c0 = v0 + tid;
#pragma unroll 2
        for (int t = t0; t < t1; ++t) {
            const float4* row = p + (size_t)t * V;
            if (c0 < V)        { float4 x = row[c0];        a0.x += x.x; a0.y += x.y; a0.z += x.z; a0.w += x.w; }
            if (c0 + 320 < V)  { float4 x = row[c0 + 320];  a1.x += x.x; a1.y += x.y; a1.z += x.z; a1.w += x.w; }
            if (c0 + 640 < V)  { float4 x = row[c0 + 640];  a2.x += x.x; a2.y += x.y; a2.z += x.z; a2.w += x.w; }
            if (c0 + 960 < V)  { float4 x = row[c0 + 960];  a3.x += x.x; a3.y += x.y; a3.z += x.z; a3.w += x.w; }
            if (c0 + 1280 < V) { float4 x = row[c0 + 1280]; a4.x += x.x; a4.y += x.y; a4.z += x.z; a4.w += x.w; }
        }
        if (c0 < V)        dst[c0]        = a0;
        if (c0 + 320 < V)  dst[c0 + 320]  = a1;
        if (c0 + 640 < V)  dst[c0 + 640]  = a2;
        if (c0 + 960 < V)  dst[c0 + 960]  = a3;
        if (c0 + 1280 < V) dst[c0 + 1280] = a4;
    }
}

// Scalar fallback for N % 4 != 0 (not expected): strided but correct.
__global__ void __launch_bounds__(256) sumT1h_k(
    const float* __restrict__ spikes, float* __restrict__ part,
    int B, int T, int N, int HS) {
    const int r = blockIdx.y;
    const int h = r / B;
    const int b = r - h * B;
    const int t0 = (T * h) / HS;
    const int t1 = (T * (h + 1)) / HS;
    const int n = blockIdx.x * blockDim.x + threadIdx.x;
    if (n >= N) return;
    const float* p = spikes + (size_t)b * T * N + n;
    float s = 0.f;
    for (int t = t0; t < t1; ++t) s += p[(size_t)t * N];
    part[(size_t)r * N + n] = s;
}

// Phase B: 8-way row-split segment reduce (f64 regs, static index),
// LDS combine, label histogram, mean/blend/argmax/store fused.
__global__ void __launch_bounds__(512) finalize2_k(
    const float* __restrict__ part, const int* __restrict__ labels,
    const float* __restrict__ rates, float* __restrict__ out,
    int B, int N, int NR, float alpha) {
    __shared__ int cnt[L_FIXED];
    __shared__ short slab[2048];
    __shared__ double red[8][64][L_FIXED];   // 40 KB

    const int tid = threadIdx.x;
    if (tid < L_FIXED) cnt[tid] = 0;
    __syncthreads();
    const bool use_slab = (NR <= 2048);
    const int HS = NR / B;
    for (int i = tid; i < B; i += blockDim.x) {
        const int lb = labels[i];
        atomicAdd(&cnt[lb], 1);
        if (use_slab)
            for (int h = 0; h < HS; ++h) slab[h * B + i] = (short)lb;
    }
    __syncthreads();

    const int lane = tid & 63;
    const int q = tid >> 6;                  // 0..7
    const int n = blockIdx.x * 64 + lane;

    double a[L_FIXED];
#pragma unroll
    for (int l = 0; l < L_FIXED; ++l) a[l] = 0.0;

    if (n < N) {
        if (use_slab) {
#pragma unroll 4
            for (int r = q; r < NR; r += 8) {
                const float s = part[(size_t)r * N + n];
                const int lab = slab[r];
#pragma unroll
                for (int l = 0; l < L_FIXED; ++l)
                    if (lab == l) a[l] += (double)s;
            }
        } else {
            for (int r = q; r < NR; r += 8) {
                const float s = part[(size_t)r * N + n];
                const int lab = labels[r % B];
#pragma unroll
                for (int l = 0; l < L_FIXED; ++l)
                    if (lab == l) a[l] += (double)s;
            }
        }
    }
#pragma unroll
    for (int l = 0; l < L_FIXED; ++l) red[q][lane][l] = a[l];
    __syncthreads();

    if (q == 0 && n < N) {
        float best = -INFINITY;
        int bi = 0;
#pragma unroll
        for (int l = 0; l < L_FIXED; ++l) {
            double s = 0.0;
#pragma unroll
            for (int qq = 0; qq < 8; ++qq) s += red[qq][lane][l];
            const int c = cnt[l];
            const float r0 = rates[(size_t)n * L_FIXED + l];
            const float v = (c > 0) ? (alpha * r0 + (float)(s / (double)c)) : r0;
            out[(size_t)N + (size_t)n * L_FIXED + l] = v;
            if (v > best) { best = v; bi = l; }  // strict > => first max (jnp.argmax)
        }
        out[n] = (float)bi;
    }
}

// ================================ LAUNCH ===================================

extern "C" void kernel_launch(void* const* d_in, const int* in_sizes, int n_in,
                              void* d_out, int out_size, void* d_ws, size_t ws_size,
                              hipStream_t stream) {
    const float* spikes = (const float*)d_in[0];
    const int*   labels = (const int*)d_in[1];
    const float* rates  = (const float*)d_in[2];
    const int L = L_FIXED;
    const int B = in_sizes[1];
    const int N = in_sizes[2] / L;
    const int T = in_sizes[0] / (B * N);
    float* out = (float*)d_out;
    float* part = (float*)d_ws;

    int HS = (T >= 2) ? 2 : 1;
    if ((size_t)HS * B * N * sizeof(float) > ws_size) HS = 1;
    const int NR = HS * B;

    if ((N & 3) == 0) {
        // PROBE: launch phase A twice (idempotent). dur_us delta vs R3
        // measures one dispatch's true cost.
        sumT_lin_k<<<dim3(NR), dim3(320), 0, stream>>>(spikes, part, B, T, N, HS);
        sumT_lin_k<<<dim3(NR), dim3(320), 0, stream>>>(spikes, part, B, T, N, HS);
    } else {
        dim3 g((N + 255) / 256, NR);
        sumT1h_k<<<g, dim3(256), 0, stream>>>(spikes, part, B, T, N, HS);
        sumT1h_k<<<g, dim3(256), 0, stream>>>(spikes, part, B, T, N, HS);
    }

    finalize2_k<<<dim3((N + 63) / 64), dim3(512), 0, stream>>>(
        part, labels, rates, out, B, N, NR, 1.0f);
}